// Round 4
// baseline (367.678 us; speedup 1.0000x reference)
//
#include <hip/hip_runtime.h>
#include <math.h>

#define EPS  1e-5f
#define EPS2 1e-10f
#define MAXN (1.0f - EPS)

#if __has_builtin(__builtin_amdgcn_sqrtf)
static __device__ __forceinline__ float fast_sqrt(float x) { return __builtin_amdgcn_sqrtf(x); }
#else
static __device__ __forceinline__ float fast_sqrt(float x) { return sqrtf(x); }
#endif
#if __has_builtin(__builtin_amdgcn_rsqf)
static __device__ __forceinline__ float fast_rsq(float x) { return __builtin_amdgcn_rsqf(x); }
#else
static __device__ __forceinline__ float fast_rsq(float x) { return 1.0f / sqrtf(x); }
#endif

// DPP cross-lane: pure VALU, never touches the LDS pipe
template <int CTRL>
static __device__ __forceinline__ float qperm(float x) {
  return __int_as_float(__builtin_amdgcn_update_dpp(
      __float_as_int(x), __float_as_int(x), CTRL, 0xF, 0xF, false));
}
#define QP_XOR1    0xB1   // quad_perm [1,0,3,2]
#define QP_XOR2    0x4E   // quad_perm [2,3,0,1]
#define QP_HALFMIR 0x141  // row_half_mirror: lane -> lane^7 within 8 (xor4 once quads uniform)

// ---------- block reduction helpers (256 threads = 4 waves) ----------
static __device__ __forceinline__ float block_sum(float v, float* red4) {
#pragma unroll
  for (int m = 32; m; m >>= 1) v += __shfl_xor(v, m, 64);
  if ((threadIdx.x & 63) == 0) red4[threadIdx.x >> 6] = v;
  __syncthreads();
  v = red4[0] + red4[1] + red4[2] + red4[3];
  __syncthreads();
  return v;
}

// ---------- K1: x -> logmap0(project(x)) ----------
__global__ __launch_bounds__(256) void k_logmap(const float* __restrict__ s0,
                                                const float* __restrict__ s1,
                                                const float* __restrict__ s2,
                                                float* __restrict__ dst, int layout) {
  const int n = blockIdx.x, z = blockIdx.y, t = threadIdx.x;
  const float* src = (z == 0) ? s0 : ((z == 1) ? s1 : s2);
  const int e0 = t * 2;
  float2 xv;
  if (layout == 0) {
    xv = *(const float2*)&src[(size_t)n * 512 + e0];
  } else {
    const int b = n >> 9, s = n & 511, h = e0 >> 6, d = e0 & 63;
    xv = *(const float2*)&src[(((size_t)(b * 8 + h) * 512 + s) * 64 + d)];
  }
  __shared__ float red4[4];
  const float ss = block_sum(xv.x * xv.x + xv.y * xv.y, red4);
  const float r = sqrtf(fmaxf(ss, EPS2));
  float f;
  if (r >= MAXN) {
    const float at = 0.5f * logf((r * (2.0f - EPS) + EPS) / (EPS * (1.0f + r)));
    f = (1.0f + EPS) * at / r;
  } else {
    const float at = 0.5f * logf((1.0f + r) / (1.0f - r));
    f = (1.0f + EPS) * at / r;
  }
  float2 o; o.x = f * xv.x; o.y = f * xv.y;
  *(float2*)&dst[((size_t)z * 2048 + n) * 512 + e0] = o;
}

// ---------- K2a: QKV GEMM, 128x128 tile, 8x8 acc/thread ----------
__global__ __launch_bounds__(256) void k_gemm_big(const float* __restrict__ Abase,
                                                  const float* __restrict__ W0,
                                                  const float* __restrict__ W1,
                                                  const float* __restrict__ W2,
                                                  float* __restrict__ Cbase) {
  const int z = blockIdx.z;
  const float* A = Abase + (size_t)z * (2048 * 512);
  const float* W = (z == 0) ? W0 : ((z == 1) ? W1 : W2);
  float* C = Cbase + (size_t)z * (2048 * 512);
  __shared__ __align__(16) float As[16][132];
  __shared__ __align__(16) float Ws[16][132];
  const int t = threadIdx.x;
  const int n0 = blockIdx.x * 128, m0 = blockIdx.y * 128;
  const int tx = t & 15, ty = t >> 4;
  const int lr = t >> 2, lk = (t & 3) * 4;    // 64 rows x 16 k per sweep
  float acc[8][8] = {};
  for (int k0 = 0; k0 < 512; k0 += 16) {
    const float4 a0 = *(const float4*)&A[(size_t)(n0 + lr) * 512 + k0 + lk];
    const float4 a1 = *(const float4*)&A[(size_t)(n0 + lr + 64) * 512 + k0 + lk];
    const float4 w0 = *(const float4*)&W[(size_t)(m0 + lr) * 512 + k0 + lk];
    const float4 w1 = *(const float4*)&W[(size_t)(m0 + lr + 64) * 512 + k0 + lk];
    __syncthreads();
    As[lk + 0][lr] = a0.x; As[lk + 1][lr] = a0.y; As[lk + 2][lr] = a0.z; As[lk + 3][lr] = a0.w;
    As[lk + 0][lr + 64] = a1.x; As[lk + 1][lr + 64] = a1.y; As[lk + 2][lr + 64] = a1.z; As[lk + 3][lr + 64] = a1.w;
    Ws[lk + 0][lr] = w0.x; Ws[lk + 1][lr] = w0.y; Ws[lk + 2][lr] = w0.z; Ws[lk + 3][lr] = w0.w;
    Ws[lk + 0][lr + 64] = w1.x; Ws[lk + 1][lr + 64] = w1.y; Ws[lk + 2][lr + 64] = w1.z; Ws[lk + 3][lr + 64] = w1.w;
    __syncthreads();
#pragma unroll
    for (int kk = 0; kk < 16; ++kk) {
      const float4 av0 = *(const float4*)&As[kk][ty * 4];
      const float4 av1 = *(const float4*)&As[kk][64 + ty * 4];
      const float4 bv0 = *(const float4*)&Ws[kk][tx * 4];
      const float4 bv1 = *(const float4*)&Ws[kk][64 + tx * 4];
      const float a[8] = {av0.x, av0.y, av0.z, av0.w, av1.x, av1.y, av1.z, av1.w};
      const float b[8] = {bv0.x, bv0.y, bv0.z, bv0.w, bv1.x, bv1.y, bv1.z, bv1.w};
#pragma unroll
      for (int i = 0; i < 8; ++i)
#pragma unroll
        for (int jj = 0; jj < 8; ++jj) acc[i][jj] = fmaf(a[i], b[jj], acc[i][jj]);
    }
  }
#pragma unroll
  for (int i = 0; i < 8; ++i) {
    const int row = n0 + ((i < 4) ? (ty * 4 + i) : (64 + ty * 4 + i - 4));
    float4 s0; s0.x = acc[i][0]; s0.y = acc[i][1]; s0.z = acc[i][2]; s0.w = acc[i][3];
    float4 s1; s1.x = acc[i][4]; s1.y = acc[i][5]; s1.z = acc[i][6]; s1.w = acc[i][7];
    *(float4*)&C[(size_t)row * 512 + m0 + tx * 4] = s0;
    *(float4*)&C[(size_t)row * 512 + m0 + 64 + tx * 4] = s1;
  }
}

// ---------- K2b: 64x64-tile GEMM (full-coverage grid for the Wo GEMM) ----------
__global__ __launch_bounds__(256) void k_gemm(const float* __restrict__ Abase,
                                              const float* __restrict__ W0,
                                              const float* __restrict__ W1,
                                              const float* __restrict__ W2,
                                              float* __restrict__ Cbase) {
  const int z = blockIdx.z;
  const float* A = Abase + (size_t)z * (2048 * 512);
  const float* W = (z == 0) ? W0 : ((z == 1) ? W1 : W2);
  float* C = Cbase + (size_t)z * (2048 * 512);
  __shared__ __align__(16) float As[32][68];
  __shared__ __align__(16) float Ws[32][68];
  const int t = threadIdx.x;
  const int n0 = blockIdx.x * 64, m0 = blockIdx.y * 64;
  const int tx = t & 15, ty = t >> 4;
  const int lr = t >> 3, lk = (t & 7) * 4;
  float acc[4][4] = {};
  for (int k0 = 0; k0 < 512; k0 += 32) {
    const float4 a0 = *(const float4*)&A[(size_t)(n0 + lr) * 512 + k0 + lk];
    const float4 a1 = *(const float4*)&A[(size_t)(n0 + lr + 32) * 512 + k0 + lk];
    const float4 w0 = *(const float4*)&W[(size_t)(m0 + lr) * 512 + k0 + lk];
    const float4 w1 = *(const float4*)&W[(size_t)(m0 + lr + 32) * 512 + k0 + lk];
    __syncthreads();
    As[lk + 0][lr] = a0.x; As[lk + 1][lr] = a0.y; As[lk + 2][lr] = a0.z; As[lk + 3][lr] = a0.w;
    As[lk + 0][lr + 32] = a1.x; As[lk + 1][lr + 32] = a1.y; As[lk + 2][lr + 32] = a1.z; As[lk + 3][lr + 32] = a1.w;
    Ws[lk + 0][lr] = w0.x; Ws[lk + 1][lr] = w0.y; Ws[lk + 2][lr] = w0.z; Ws[lk + 3][lr] = w0.w;
    Ws[lk + 0][lr + 32] = w1.x; Ws[lk + 1][lr + 32] = w1.y; Ws[lk + 2][lr + 32] = w1.z; Ws[lk + 3][lr + 32] = w1.w;
    __syncthreads();
#pragma unroll
    for (int kk = 0; kk < 32; ++kk) {
      const float4 av = *(const float4*)&As[kk][ty * 4];
      const float4 wv = *(const float4*)&Ws[kk][tx * 4];
      const float a[4] = {av.x, av.y, av.z, av.w};
      const float b[4] = {wv.x, wv.y, wv.z, wv.w};
#pragma unroll
      for (int i = 0; i < 4; ++i)
#pragma unroll
        for (int j = 0; j < 4; ++j) acc[i][j] = fmaf(a[i], b[j], acc[i][j]);
    }
  }
#pragma unroll
  for (int i = 0; i < 4; ++i) {
    float4 st; st.x = acc[i][0]; st.y = acc[i][1]; st.z = acc[i][2]; st.w = acc[i][3];
    *(float4*)&C[(size_t)(n0 + ty * 4 + i) * 512 + m0 + tx * 4] = st;
  }
}

// ---------- K3: expmap0 + mobius-add bias; optional per-head project + norms ----------
__global__ __launch_bounds__(256) void k_post(const float* __restrict__ tin,
                                              const float* __restrict__ b0,
                                              const float* __restrict__ b1,
                                              const float* __restrict__ b2,
                                              float* __restrict__ o0, float* __restrict__ o1,
                                              float* __restrict__ o2,
                                              float* __restrict__ nrm0, float* __restrict__ nrm1,
                                              float* __restrict__ nrm2, int final_mode) {
  const int nrow = blockIdx.x, z = blockIdx.y, t = threadIdx.x;
  const float* tv = tin + ((size_t)z * 2048 + nrow) * 512;
  const float* bias = (z == 0) ? b0 : ((z == 1) ? b1 : b2);
  const int e0 = 2 * t;
  const float2 tp = *(const float2*)&tv[e0];
  const float2 bp = *(const float2*)&bias[e0];
  float p_tt = tp.x * tp.x + tp.y * tp.y;
  float p_tb = tp.x * bp.x + tp.y * bp.y;
  float p_bb = bp.x * bp.x + bp.y * bp.y;
#pragma unroll
  for (int m = 32; m; m >>= 1) {
    p_tt += __shfl_xor(p_tt, m, 64);
    p_tb += __shfl_xor(p_tb, m, 64);
    p_bb += __shfl_xor(p_bb, m, 64);
  }
  __shared__ float red[4][3];
  const int lane = t & 63, w = t >> 6;
  if (lane == 0) { red[w][0] = p_tt; red[w][1] = p_tb; red[w][2] = p_bb; }
  __syncthreads();
  const float s_tt = red[0][0] + red[1][0] + red[2][0] + red[3][0];
  const float s_tb = red[0][1] + red[1][1] + red[2][1] + red[3][1];
  const float s_bb = red[0][2] + red[1][2] + red[2][2] + red[3][2];
  const float tn = sqrtf(fmaxf(s_tt, EPS2));
  const float th = tanhf(tn / (1.0f + EPS));
  const float g = th / tn;
  const float rnorm = th * (sqrtf(s_tt) / tn);
  const float sr = (rnorm >= MAXN) ? (MAXN / (rnorm + EPS)) : 1.0f;
  const float gr = g * sr;
  const float rn = (rnorm * sr) * (rnorm * sr);
  const float bnorm = sqrtf(fmaxf(s_bb, EPS2));
  const float sb = (bnorm >= MAXN) ? (MAXN / (bnorm + EPS)) : 1.0f;
  const float xy = gr * sb * s_tb;
  const float yn = (sb * sb) * s_bb;
  const float Af = 1.0f + 2.0f * xy + yn;
  const float Cf = 1.0f - rn;
  const float den = 1.0f + 2.0f * xy + rn * yn + EPS;
  const float id = 1.0f / den;
  const float on_raw = (Af * Af * rn + 2.0f * Af * Cf * xy + Cf * Cf * yn) * (id * id);
  const float no = sqrtf(fmaxf(on_raw, EPS2));
  const float so = (no >= MAXN) ? (MAXN / (no + EPS)) : 1.0f;
  const float ms = id * so;
  const float ca = gr * Af * ms;
  const float cb = sb * Cf * ms;
  const float v0 = ca * tp.x + cb * bp.x;
  const float v1 = ca * tp.y + cb * bp.y;
  if (final_mode) {
    float2 o; o.x = v0; o.y = v1;
    *(float2*)&o0[(size_t)nrow * 512 + e0] = o;
    return;
  }
  float hp = v0 * v0 + v1 * v1;
#pragma unroll
  for (int m = 16; m; m >>= 1) hp += __shfl_xor(hp, m, 64);
  const float hnr = sqrtf(fmaxf(hp, EPS2));
  float sh = 1.0f;
  if (z != 2) sh = (hnr >= MAXN) ? (MAXN / (hnr + EPS)) : 1.0f;
  float* outz = (z == 0) ? o0 : ((z == 1) ? o1 : o2);
  float* nz = (z == 0) ? nrm0 : ((z == 1) ? nrm1 : nrm2);
  const int b = nrow >> 9, s = nrow & 511, h = e0 >> 6, d = e0 & 63;
  float2 o; o.x = v0 * sh; o.y = v1 * sh;
  *(float2*)&outz[(((size_t)(b * 8 + h) * 512 + s) * 64 + d)] = o;
  if ((t & 31) == 0) nz[(size_t)(b * 8 + h) * 512 + s] = hp * sh * sh;
}

// ---------- K4: -dist logits [32,512,512] ----------
__global__ __launch_bounds__(256) void k_logits(const float* __restrict__ Q,
                                                const float* __restrict__ K,
                                                const float* __restrict__ qn,
                                                const float* __restrict__ kn,
                                                float* __restrict__ attn) {
  const int bh = blockIdx.z;
  const int i0 = blockIdx.x * 64;
  const int j0 = blockIdx.y * 128;
  const float* Qb = Q + (size_t)bh * 512 * 64;
  const float* Kb = K + (size_t)bh * 512 * 64;
  __shared__ __align__(16) float q_lds[64][68];
  __shared__ __align__(16) float k_lds[128][68];
  const int t = threadIdx.x;
  const int tx = t & 15, ty = t >> 4;
  const int tx4 = tx * 4;
#pragma unroll
  for (int it = 0; it < 4; ++it) {
    const int row = it * 16 + ty;
    *(float4*)&q_lds[row][tx4] = *(const float4*)&Qb[(size_t)(i0 + row) * 64 + tx4];
  }
#pragma unroll
  for (int it = 0; it < 8; ++it) {
    const int row = it * 16 + ty;
    *(float4*)&k_lds[row][tx4] = *(const float4*)&Kb[(size_t)(j0 + row) * 64 + tx4];
  }
  __syncthreads();
  float acc[4][8] = {};
#pragma unroll
  for (int d = 0; d < 64; d += 4) {
    float4 qv[4], kv[8];
#pragma unroll
    for (int i = 0; i < 4; ++i) qv[i] = *(const float4*)&q_lds[ty * 4 + i][d];
#pragma unroll
    for (int j = 0; j < 8; ++j) kv[j] = *(const float4*)&k_lds[tx + 16 * j][d];
#pragma unroll
    for (int i = 0; i < 4; ++i)
#pragma unroll
      for (int j = 0; j < 8; ++j) {
        acc[i][j] = fmaf(qv[i].x, kv[j].x, acc[i][j]);
        acc[i][j] = fmaf(qv[i].y, kv[j].y, acc[i][j]);
        acc[i][j] = fmaf(qv[i].z, kv[j].z, acc[i][j]);
        acc[i][j] = fmaf(qv[i].w, kv[j].w, acc[i][j]);
      }
  }
  float qni[4], knj[8];
#pragma unroll
  for (int i = 0; i < 4; ++i) qni[i] = qn[(size_t)bh * 512 + i0 + ty * 4 + i];
#pragma unroll
  for (int j = 0; j < 8; ++j) knj[j] = kn[(size_t)bh * 512 + j0 + tx + 16 * j];
#pragma unroll
  for (int i = 0; i < 4; ++i)
#pragma unroll
    for (int j = 0; j < 8; ++j) {
      const float num = fmaxf(qni[i] + knj[j] - 2.0f * acc[i][j], 0.0f);
      const float den = fmaxf((1.0f - qni[i]) * (1.0f - knj[j]), EPS);
      const float wv = 2.0f * num / den + EPS;
      const float dist = logf(1.0f + wv + sqrtf(wv * (wv + 2.0f)));
      attn[((size_t)bh * 512 + i0 + ty * 4 + i) * 512 + j0 + tx + 16 * j] = -dist;
    }
}

// ---------- K5: in-place row softmax over 512 ----------
__global__ __launch_bounds__(256) void k_softmax(float* __restrict__ attn) {
  const int row = blockIdx.x, t = threadIdx.x;
  float* p = attn + (size_t)row * 512;
  const float2 x = *(const float2*)&p[2 * t];
  __shared__ float red4[4];
  float m = fmaxf(x.x, x.y);
#pragma unroll
  for (int mk = 32; mk; mk >>= 1) m = fmaxf(m, __shfl_xor(m, mk, 64));
  if ((t & 63) == 0) red4[t >> 6] = m;
  __syncthreads();
  m = fmaxf(fmaxf(red4[0], red4[1]), fmaxf(red4[2], red4[3]));
  __syncthreads();
  const float e0 = expf(x.x - m), e1 = expf(x.y - m);
  float s = e0 + e1;
#pragma unroll
  for (int mk = 32; mk; mk >>= 1) s += __shfl_xor(s, mk, 64);
  if ((t & 63) == 0) red4[t >> 6] = s;
  __syncthreads();
  s = red4[0] + red4[1] + red4[2] + red4[3];
  const float inv = 1.0f / s;
  float2 o; o.x = e0 * inv; o.y = e1 * inv;
  *(float2*)&p[2 * t] = o;
}

// ---------- K6 v4: mobius scan, 8 lanes/row -> 2048 waves = 2/SIMD ----------
// Cross-lane dot via 3 DPP adds (xor1, xor2 quad_perm; xor4 row_half_mirror).
// Clamp test on squared norm (no sqrt); so via native rsq with EPS correction.
__global__ __launch_bounds__(256) void k_scan(const float* __restrict__ V,
                                              const float* __restrict__ vn,
                                              const float* __restrict__ attnw,
                                              float* __restrict__ att) {
  __shared__ __align__(16) float v_lds[64 * 64];      // [j][d] chunk (16 KB)
  __shared__ __align__(16) float swyn_lds[64 * 66];   // [j][row*2] stride 66 (16.9 KB)
  const int blk = blockIdx.x;
  const int bh = blk >> 4;            // 32 bh
  const int i0 = (blk & 15) * 32;     // 16 chunks of 32 rows
  const int t = threadIdx.x;
  const int lane = t & 63, w = t >> 6;
  const int row_blk = w * 8 + (lane >> 3);  // 0..31
  const int sub = lane & 7;                 // 8-float d-segment
  const int d0 = sub * 8;
  const float* Vb = V + (size_t)bh * 512 * 64;
  const float* vnb = vn + (size_t)bh * 512;
  const float* arow_base = attnw + ((size_t)bh * 512 + i0 + row_blk) * 512;

  float ws[8];
#pragma unroll
  for (int k = 0; k < 8; ++k) ws[k] = 0.0f;
  float xn = 0.0f;

  for (int jc = 0; jc < 512; jc += 64) {
    // ---- stage V chunk (64x64, coalesced float4) ----
#pragma unroll
    for (int it = 0; it < 4; ++it) {
      const int idx4 = it * 256 + t;
      *(float4*)&v_lds[idx4 * 4] = *(const float4*)&Vb[(size_t)jc * 64 + idx4 * 4];
    }
    // ---- this lane: its row's weights at j in [sub*8, sub*8+8) ----
    const float4 aw0 = *(const float4*)&arow_base[jc + sub * 8];
    const float4 aw1 = *(const float4*)&arow_base[jc + sub * 8 + 4];
    const float4 vq0 = *(const float4*)&vnb[jc + sub * 8];
    const float4 vq1 = *(const float4*)&vnb[jc + sub * 8 + 4];
    const float wq[8] = {aw0.x, aw0.y, aw0.z, aw0.w, aw1.x, aw1.y, aw1.z, aw1.w};
    const float vq[8] = {vq0.x, vq0.y, vq0.z, vq0.w, vq1.x, vq1.y, vq1.z, vq1.w};
#pragma unroll
    for (int e = 0; e < 8; ++e) {
      const float wgt = wq[e];
      const float ynr = wgt * wgt * vq[e];
      const float ny = fast_sqrt(fmaxf(ynr, EPS2));
      const float sy = (ny >= MAXN) ? (MAXN * __builtin_amdgcn_rcpf(ny + EPS)) : 1.0f;
      float2 p; p.x = sy * wgt; p.y = (sy * sy) * ynr;
      *(float2*)&swyn_lds[(sub * 8 + e) * 66 + row_blk * 2] = p;
    }
    __syncthreads();

    // ---- 64 sequential mobius steps ----
#pragma unroll 4
    for (int j = 0; j < 64; ++j) {
      const float2 sy2 = *(const float2*)&swyn_lds[j * 66 + row_blk * 2];
      const float4 v0 = *(const float4*)&v_lds[j * 64 + d0];
      const float4 v1 = *(const float4*)&v_lds[j * 64 + d0 + 4];
      float da = ws[0] * v0.x;
      da = fmaf(ws[1], v0.y, da); da = fmaf(ws[2], v0.z, da); da = fmaf(ws[3], v0.w, da);
      float db = ws[4] * v1.x;
      db = fmaf(ws[5], v1.y, db); db = fmaf(ws[6], v1.z, db); db = fmaf(ws[7], v1.w, db);
      float d = da + db;
      d += qperm<QP_XOR1>(d);
      d += qperm<QP_XOR2>(d);
      d += qperm<QP_HALFMIR>(d);        // full dot(ws, v_j) across the 8-lane row
      const float sw = sy2.x, yn = sy2.y;
      const float ynp1 = 1.0f + yn;     // off critical chain (yn from LDS)
      const float xy = sw * d;
      const float Cf = 1.0f - xn;
      const float den = fmaf(2.0f, xy, fmaf(xn, yn, 1.0f + EPS));
      const float Af = fmaf(2.0f, xy, ynp1);
      const float id = __builtin_amdgcn_rcpf(den);
      const float A2 = Af * Af, CC = Cf * Cf, AC = Af * Cf;
      const float txy = xy + xy;
      const float onn = fmaf(A2, xn, fmaf(CC, yn, txy * AC));
      const float id2 = id * id;
      const float on_raw = onn * id2;
      const float rs = fast_rsq(fmaxf(on_raw, EPS2));
      const float so_c = (MAXN * rs) * fmaf(-EPS, rs, 1.0f);  // = MAXN/(no+EPS) + O(EPS^2)
      const float so = (on_raw >= MAXN * MAXN) ? so_c : 1.0f;
      const float ms = id * so;
      const float am = Af * ms;
      const float cm = (Cf * sw) * ms;
      ws[0] = fmaf(am, ws[0], cm * v0.x); ws[1] = fmaf(am, ws[1], cm * v0.y);
      ws[2] = fmaf(am, ws[2], cm * v0.z); ws[3] = fmaf(am, ws[3], cm * v0.w);
      ws[4] = fmaf(am, ws[4], cm * v1.x); ws[5] = fmaf(am, ws[5], cm * v1.y);
      ws[6] = fmaf(am, ws[6], cm * v1.z); ws[7] = fmaf(am, ws[7], cm * v1.w);
      xn = (on_raw * so) * so;
    }
    __syncthreads();
  }
  // epilogue: this lane's 8-float segment of its row
  float* o = att + (((size_t)bh * 512 + i0 + row_blk) * 64 + d0);
  float4 s0; s0.x = ws[0]; s0.y = ws[1]; s0.z = ws[2]; s0.w = ws[3];
  float4 s1; s1.x = ws[4]; s1.y = ws[5]; s1.z = ws[6]; s1.w = ws[7];
  *(float4*)&o[0] = s0;
  *(float4*)&o[4] = s1;
}

extern "C" void kernel_launch(void* const* d_in, const int* in_sizes, int n_in,
                              void* d_out, int out_size, void* d_ws, size_t ws_size,
                              hipStream_t stream) {
  const float* query = (const float*)d_in[0];
  const float* key_  = (const float*)d_in[1];
  const float* value = (const float*)d_in[2];
  const float* Wq = (const float*)d_in[3];
  const float* bq = (const float*)d_in[4];
  const float* Wk = (const float*)d_in[5];
  const float* bk = (const float*)d_in[6];
  const float* Wv = (const float*)d_in[7];
  const float* bv = (const float*)d_in[8];
  const float* Wo = (const float*)d_in[9];
  const float* bo = (const float*)d_in[10];
  float* ws = (float*)d_ws;
  const size_t M = 1u << 20;          // 1M floats
  float* Qb   = ws;                   // [32,512,64]
  float* Kb   = ws + 1 * M;
  float* Vb   = ws + 2 * M;
  float* qn   = ws + 3 * M;           // [32,512]
  float* kn   = qn + 16384;
  float* vn   = kn + 16384;
  float* attn = ws + 4 * M;           // [32,512,512]
  float* xt3  = ws + 12 * M;          // 3x [2048,512]
  float* t3   = ws + 15 * M;          // 3x [2048,512]
  float* att  = ws + 12 * M;          // reuse xt3 region after QKV done
  float* xto  = ws + 13 * M;
  float* to_  = ws + 14 * M;

  k_logmap<<<dim3(2048, 3), 256, 0, stream>>>(query, key_, value, xt3, 0);
  k_gemm_big<<<dim3(16, 4, 3), 256, 0, stream>>>(xt3, Wq, Wk, Wv, t3);
  k_post<<<dim3(2048, 3), 256, 0, stream>>>(t3, bq, bk, bv, Qb, Kb, Vb, qn, kn, vn, 0);
  k_logits<<<dim3(8, 4, 32), 256, 0, stream>>>(Qb, Kb, qn, kn, attn);
  k_softmax<<<16384, 256, 0, stream>>>(attn);
  k_scan<<<512, 256, 0, stream>>>(Vb, vn, attn, att);
  k_logmap<<<dim3(2048, 1), 256, 0, stream>>>(att, att, att, xto, 1);
  k_gemm<<<dim3(32, 8, 1), 256, 0, stream>>>(xto, Wo, Wo, Wo, to_);
  k_post<<<dim3(2048, 1), 256, 0, stream>>>(to_, bo, bo, bo, (float*)d_out,
                                            nullptr, nullptr, nullptr, nullptr, nullptr, 1);
}

// Round 5
// 323.905 us; speedup vs baseline: 1.1351x; 1.1351x over previous
//
#include <hip/hip_runtime.h>
#include <math.h>

#define EPS  1e-5f
#define EPS2 1e-10f
#define MAXN (1.0f - EPS)

// DPP cross-lane: pure VALU, never touches the LDS pipe
template <int CTRL>
static __device__ __forceinline__ float qperm(float x) {
  return __int_as_float(__builtin_amdgcn_update_dpp(
      __float_as_int(x), __float_as_int(x), CTRL, 0xF, 0xF, false));
}
#define QP_XOR1    0xB1   // quad_perm [1,0,3,2]
#define QP_XOR2    0x4E   // quad_perm [2,3,0,1]
#define QP_HALFMIR 0x141  // row_half_mirror: lane -> lane^7 within 8

// ---------- block reduction helper (256 threads = 4 waves) ----------
static __device__ __forceinline__ float block_sum(float v, float* red4) {
#pragma unroll
  for (int m = 32; m; m >>= 1) v += __shfl_xor(v, m, 64);
  if ((threadIdx.x & 63) == 0) red4[threadIdx.x >> 6] = v;
  __syncthreads();
  v = red4[0] + red4[1] + red4[2] + red4[3];
  __syncthreads();
  return v;
}

// ---------- K1: row-norm -> logmap scale factor f (one float per row) ----------
// f = (1+EPS)*atanh(n)/r with n = project-combined norm; replaces materializing
// logmap0(project(x)) since (f*x)@W^T = f*(x@W^T).
__global__ __launch_bounds__(256) void k_rownorm(const float* __restrict__ s0,
                                                 const float* __restrict__ s1,
                                                 const float* __restrict__ s2,
                                                 float* __restrict__ f) {
  const int n = blockIdx.x, z = blockIdx.y, t = threadIdx.x;
  const float* src = (z == 0) ? s0 : ((z == 1) ? s1 : s2);
  const float2 xv = *(const float2*)&src[(size_t)n * 512 + 2 * t];
  __shared__ float red4[4];
  const float ss = block_sum(xv.x * xv.x + xv.y * xv.y, red4);
  if (t == 0) {
    const float r = sqrtf(fmaxf(ss, EPS2));
    float fv;
    if (r >= MAXN) {
      // projected: stable atanh form avoids 1-n cancellation
      const float at = 0.5f * logf((r * (2.0f - EPS) + EPS) / (EPS * (1.0f + r)));
      fv = (1.0f + EPS) * at / r;
    } else {
      const float at = 0.5f * logf((1.0f + r) / (1.0f - r));
      fv = (1.0f + EPS) * at / r;
    }
    f[z * 2048 + n] = fv;
  }
}

// ---------- K2: C = f[row] * (A @ W^T); A raw inputs [2048,512] ----------
__global__ __launch_bounds__(256) void k_gemm(const float* __restrict__ A0,
                                              const float* __restrict__ A1,
                                              const float* __restrict__ A2,
                                              const float* __restrict__ W0,
                                              const float* __restrict__ W1,
                                              const float* __restrict__ W2,
                                              const float* __restrict__ fbase,
                                              float* __restrict__ Cbase) {
  const int z = blockIdx.z;
  const float* A = (z == 0) ? A0 : ((z == 1) ? A1 : A2);
  const float* W = (z == 0) ? W0 : ((z == 1) ? W1 : W2);
  float* C = Cbase + (size_t)z * (2048 * 512);
  __shared__ __align__(16) float As[32][68];
  __shared__ __align__(16) float Ws[32][68];
  const int t = threadIdx.x;
  const int n0 = blockIdx.x * 64, m0 = blockIdx.y * 64;
  const int tx = t & 15, ty = t >> 4;
  const int lr = t >> 3, lk = (t & 7) * 4;
  float acc[4][4] = {};
  for (int k0 = 0; k0 < 512; k0 += 32) {
    const float4 a0 = *(const float4*)&A[(size_t)(n0 + lr) * 512 + k0 + lk];
    const float4 a1 = *(const float4*)&A[(size_t)(n0 + lr + 32) * 512 + k0 + lk];
    const float4 w0 = *(const float4*)&W[(size_t)(m0 + lr) * 512 + k0 + lk];
    const float4 w1 = *(const float4*)&W[(size_t)(m0 + lr + 32) * 512 + k0 + lk];
    __syncthreads();
    As[lk + 0][lr] = a0.x; As[lk + 1][lr] = a0.y; As[lk + 2][lr] = a0.z; As[lk + 3][lr] = a0.w;
    As[lk + 0][lr + 32] = a1.x; As[lk + 1][lr + 32] = a1.y; As[lk + 2][lr + 32] = a1.z; As[lk + 3][lr + 32] = a1.w;
    Ws[lk + 0][lr] = w0.x; Ws[lk + 1][lr] = w0.y; Ws[lk + 2][lr] = w0.z; Ws[lk + 3][lr] = w0.w;
    Ws[lk + 0][lr + 32] = w1.x; Ws[lk + 1][lr + 32] = w1.y; Ws[lk + 2][lr + 32] = w1.z; Ws[lk + 3][lr + 32] = w1.w;
    __syncthreads();
#pragma unroll
    for (int kk = 0; kk < 32; ++kk) {
      const float4 av = *(const float4*)&As[kk][ty * 4];
      const float4 wv = *(const float4*)&Ws[kk][tx * 4];
      const float a[4] = {av.x, av.y, av.z, av.w};
      const float b[4] = {wv.x, wv.y, wv.z, wv.w};
#pragma unroll
      for (int i = 0; i < 4; ++i)
#pragma unroll
        for (int j = 0; j < 4; ++j) acc[i][j] = fmaf(a[i], b[j], acc[i][j]);
    }
  }
#pragma unroll
  for (int i = 0; i < 4; ++i) {
    const float fv = fbase[z * 2048 + n0 + ty * 4 + i];
    float4 st; st.x = fv * acc[i][0]; st.y = fv * acc[i][1];
    st.z = fv * acc[i][2]; st.w = fv * acc[i][3];
    *(float4*)&C[(size_t)(n0 + ty * 4 + i) * 512 + m0 + tx * 4] = st;
  }
}

// ---------- K3: expmap0 + mobius-add bias; per-head project + norms ----------
__global__ __launch_bounds__(256) void k_post(const float* __restrict__ tin,
                                              const float* __restrict__ b0,
                                              const float* __restrict__ b1,
                                              const float* __restrict__ b2,
                                              float* __restrict__ o0, float* __restrict__ o1,
                                              float* __restrict__ o2,
                                              float* __restrict__ nrm0, float* __restrict__ nrm1,
                                              float* __restrict__ nrm2, int final_mode) {
  const int nrow = blockIdx.x, z = blockIdx.y, t = threadIdx.x;
  const float* tv = tin + ((size_t)z * 2048 + nrow) * 512;
  const float* bias = (z == 0) ? b0 : ((z == 1) ? b1 : b2);
  const int e0 = 2 * t;
  const float2 tp = *(const float2*)&tv[e0];
  const float2 bp = *(const float2*)&bias[e0];
  float p_tt = tp.x * tp.x + tp.y * tp.y;
  float p_tb = tp.x * bp.x + tp.y * bp.y;
  float p_bb = bp.x * bp.x + bp.y * bp.y;
#pragma unroll
  for (int m = 32; m; m >>= 1) {
    p_tt += __shfl_xor(p_tt, m, 64);
    p_tb += __shfl_xor(p_tb, m, 64);
    p_bb += __shfl_xor(p_bb, m, 64);
  }
  __shared__ float red[4][3];
  const int lane = t & 63, w = t >> 6;
  if (lane == 0) { red[w][0] = p_tt; red[w][1] = p_tb; red[w][2] = p_bb; }
  __syncthreads();
  const float s_tt = red[0][0] + red[1][0] + red[2][0] + red[3][0];
  const float s_tb = red[0][1] + red[1][1] + red[2][1] + red[3][1];
  const float s_bb = red[0][2] + red[1][2] + red[2][2] + red[3][2];
  const float tn = sqrtf(fmaxf(s_tt, EPS2));
  const float th = tanhf(tn / (1.0f + EPS));
  const float g = th / tn;
  const float rnorm = th * (sqrtf(s_tt) / tn);
  const float sr = (rnorm >= MAXN) ? (MAXN / (rnorm + EPS)) : 1.0f;
  const float gr = g * sr;
  const float rn = (rnorm * sr) * (rnorm * sr);
  const float bnorm = sqrtf(fmaxf(s_bb, EPS2));
  const float sb = (bnorm >= MAXN) ? (MAXN / (bnorm + EPS)) : 1.0f;
  const float xy = gr * sb * s_tb;
  const float yn = (sb * sb) * s_bb;
  const float Af = 1.0f + 2.0f * xy + yn;
  const float Cf = 1.0f - rn;
  const float den = 1.0f + 2.0f * xy + rn * yn + EPS;
  const float id = 1.0f / den;
  const float on_raw = (Af * Af * rn + 2.0f * Af * Cf * xy + Cf * Cf * yn) * (id * id);
  const float no = sqrtf(fmaxf(on_raw, EPS2));
  const float so = (no >= MAXN) ? (MAXN / (no + EPS)) : 1.0f;
  const float ms = id * so;
  const float ca = gr * Af * ms;
  const float cb = sb * Cf * ms;
  const float v0 = ca * tp.x + cb * bp.x;
  const float v1 = ca * tp.y + cb * bp.y;
  if (final_mode) {
    float2 o; o.x = v0; o.y = v1;
    *(float2*)&o0[(size_t)nrow * 512 + e0] = o;
    return;
  }
  float hp = v0 * v0 + v1 * v1;
#pragma unroll
  for (int m = 16; m; m >>= 1) hp += __shfl_xor(hp, m, 64);
  const float hnr = sqrtf(fmaxf(hp, EPS2));
  float sh = 1.0f;
  if (z != 2) sh = (hnr >= MAXN) ? (MAXN / (hnr + EPS)) : 1.0f;
  float* outz = (z == 0) ? o0 : ((z == 1) ? o1 : o2);
  float* nz = (z == 0) ? nrm0 : ((z == 1) ? nrm1 : nrm2);
  const int b = nrow >> 9, s = nrow & 511, h = e0 >> 6, d = e0 & 63;
  float2 o; o.x = v0 * sh; o.y = v1 * sh;
  *(float2*)&outz[(((size_t)(b * 8 + h) * 512 + s) * 64 + d)] = o;
  if ((t & 31) == 0) nz[(size_t)(b * 8 + h) * 512 + s] = hp * sh * sh;
}

// ---------- K4: r = exp(-dist) EXACTLY = 1/(z+sqrt(z^2-1)); row-sums via atomics ----------
__global__ __launch_bounds__(256) void k_logits(const float* __restrict__ Q,
                                                const float* __restrict__ K,
                                                const float* __restrict__ qn,
                                                const float* __restrict__ kn,
                                                float* __restrict__ attn,
                                                float* __restrict__ rowsum) {
  const int bh = blockIdx.z;
  const int i0 = blockIdx.x * 64;
  const int j0 = blockIdx.y * 128;
  const float* Qb = Q + (size_t)bh * 512 * 64;
  const float* Kb = K + (size_t)bh * 512 * 64;
  __shared__ __align__(16) float q_lds[64][68];
  __shared__ __align__(16) float k_lds[128][68];
  const int t = threadIdx.x;
  const int tx = t & 15, ty = t >> 4;
  const int tx4 = tx * 4;
#pragma unroll
  for (int it = 0; it < 4; ++it) {
    const int row = it * 16 + ty;
    *(float4*)&q_lds[row][tx4] = *(const float4*)&Qb[(size_t)(i0 + row) * 64 + tx4];
  }
#pragma unroll
  for (int it = 0; it < 8; ++it) {
    const int row = it * 16 + ty;
    *(float4*)&k_lds[row][tx4] = *(const float4*)&Kb[(size_t)(j0 + row) * 64 + tx4];
  }
  __syncthreads();
  float acc[4][8] = {};
#pragma unroll
  for (int d = 0; d < 64; d += 4) {
    float4 qv[4], kv[8];
#pragma unroll
    for (int i = 0; i < 4; ++i) qv[i] = *(const float4*)&q_lds[ty * 4 + i][d];
#pragma unroll
    for (int j = 0; j < 8; ++j) kv[j] = *(const float4*)&k_lds[tx + 16 * j][d];
#pragma unroll
    for (int i = 0; i < 4; ++i)
#pragma unroll
      for (int j = 0; j < 8; ++j) {
        acc[i][j] = fmaf(qv[i].x, kv[j].x, acc[i][j]);
        acc[i][j] = fmaf(qv[i].y, kv[j].y, acc[i][j]);
        acc[i][j] = fmaf(qv[i].z, kv[j].z, acc[i][j]);
        acc[i][j] = fmaf(qv[i].w, kv[j].w, acc[i][j]);
      }
  }
  float qni[4], knj[8];
#pragma unroll
  for (int i = 0; i < 4; ++i) qni[i] = qn[(size_t)bh * 512 + i0 + ty * 4 + i];
#pragma unroll
  for (int j = 0; j < 8; ++j) knj[j] = kn[(size_t)bh * 512 + j0 + tx + 16 * j];
  float rs_[4] = {};
#pragma unroll
  for (int i = 0; i < 4; ++i)
#pragma unroll
    for (int j = 0; j < 8; ++j) {
      const float num = fmaxf(qni[i] + knj[j] - 2.0f * acc[i][j], 0.0f);
      const float den = fmaxf((1.0f - qni[i]) * (1.0f - knj[j]), EPS);
      const float wv = 2.0f * num / den + EPS;
      // exp(-acosh(1+wv)) = 1/(1+wv+sqrt(wv*(wv+2))) exactly -> softmax without exp
      const float s_ = 1.0f + wv + sqrtf(wv * (wv + 2.0f));
      const float r = __builtin_amdgcn_rcpf(s_);
      rs_[i] += r;
      attn[((size_t)bh * 512 + i0 + ty * 4 + i) * 512 + j0 + tx + 16 * j] = r;
    }
#pragma unroll
  for (int i = 0; i < 4; ++i) {
    float v = rs_[i];
    v += __shfl_xor(v, 1, 64); v += __shfl_xor(v, 2, 64);
    v += __shfl_xor(v, 4, 64); v += __shfl_xor(v, 8, 64);
    if (tx == 0) atomicAdd(&rowsum[(size_t)bh * 512 + i0 + ty * 4 + i], v);
  }
}

// ---------- K6 v5: mobius scan, 8 lanes/row, slimmed chain ----------
// sy == 1 (wgt<=1, |v_head|<1); so-clamp dropped (gyro-triangle bound: xn << 1).
// Softmax normalization fused (weights = r * rcp(rowsum)). Output in [B,S,E].
__global__ __launch_bounds__(256) void k_scan(const float* __restrict__ V,
                                              const float* __restrict__ vn,
                                              const float* __restrict__ rw,
                                              const float* __restrict__ rowsum,
                                              float* __restrict__ att) {
  __shared__ __align__(16) float v_lds[64 * 64];
  __shared__ __align__(16) float swyn_lds[64 * 66];
  const int blk = blockIdx.x;
  const int bh = blk >> 4;
  const int i0 = (blk & 15) * 32;
  const int t = threadIdx.x;
  const int lane = t & 63, w = t >> 6;
  const int row_blk = w * 8 + (lane >> 3);
  const int sub = lane & 7;
  const int d0 = sub * 8;
  const float* Vb = V + (size_t)bh * 512 * 64;
  const float* vnb = vn + (size_t)bh * 512;
  const float* arow = rw + ((size_t)bh * 512 + i0 + row_blk) * 512;
  const float inv_s = __builtin_amdgcn_rcpf(rowsum[(size_t)bh * 512 + i0 + row_blk]);

  float ws[8];
#pragma unroll
  for (int k = 0; k < 8; ++k) ws[k] = 0.0f;
  float xn = 0.0f;

  for (int jc = 0; jc < 512; jc += 64) {
#pragma unroll
    for (int it = 0; it < 4; ++it) {
      const int idx4 = it * 256 + t;
      *(float4*)&v_lds[idx4 * 4] = *(const float4*)&Vb[(size_t)jc * 64 + idx4 * 4];
    }
    const float4 a0 = *(const float4*)&arow[jc + sub * 8];
    const float4 a1 = *(const float4*)&arow[jc + sub * 8 + 4];
    const float4 n0 = *(const float4*)&vnb[jc + sub * 8];
    const float4 n1 = *(const float4*)&vnb[jc + sub * 8 + 4];
    const float wq[8] = {a0.x, a0.y, a0.z, a0.w, a1.x, a1.y, a1.z, a1.w};
    const float nq[8] = {n0.x, n0.y, n0.z, n0.w, n1.x, n1.y, n1.z, n1.w};
#pragma unroll
    for (int e = 0; e < 8; ++e) {
      const float wgt = wq[e] * inv_s;
      float2 p; p.x = wgt; p.y = (wgt * wgt) * nq[e];
      *(float2*)&swyn_lds[(sub * 8 + e) * 66 + row_blk * 2] = p;
    }
    __syncthreads();

#pragma unroll 4
    for (int j = 0; j < 64; ++j) {
      const float2 sy2 = *(const float2*)&swyn_lds[j * 66 + row_blk * 2];
      const float4 v0 = *(const float4*)&v_lds[j * 64 + d0];
      const float4 v1 = *(const float4*)&v_lds[j * 64 + d0 + 4];
      float da = ws[0] * v0.x;
      da = fmaf(ws[1], v0.y, da); da = fmaf(ws[2], v0.z, da); da = fmaf(ws[3], v0.w, da);
      float db = ws[4] * v1.x;
      db = fmaf(ws[5], v1.y, db); db = fmaf(ws[6], v1.z, db); db = fmaf(ws[7], v1.w, db);
      float d = da + db;
      d += qperm<QP_XOR1>(d);
      d += qperm<QP_XOR2>(d);
      d += qperm<QP_HALFMIR>(d);         // dot(ws, v_j) across the 8-lane row
      const float sw = sy2.x, yn = sy2.y;
      const float ynp1 = 1.0f + yn;
      const float xy = sw * d;
      const float Cf = 1.0f - xn;
      const float den = fmaf(2.0f, xy, fmaf(xn, yn, 1.0f + EPS));
      const float Af = fmaf(2.0f, xy, ynp1);
      const float id = __builtin_amdgcn_rcpf(den);
      const float A2 = Af * Af, CC = Cf * Cf, AC = Af * Cf;
      const float txy = xy + xy;
      const float onn = fmaf(A2, xn, fmaf(CC, yn, txy * AC));
      const float id2 = id * id;
      xn = onn * id2;                    // ||out||^2; in-ball by gyro-triangle bound
      const float am = Af * id;
      const float cm = (Cf * sw) * id;
      ws[0] = fmaf(am, ws[0], cm * v0.x); ws[1] = fmaf(am, ws[1], cm * v0.y);
      ws[2] = fmaf(am, ws[2], cm * v0.z); ws[3] = fmaf(am, ws[3], cm * v0.w);
      ws[4] = fmaf(am, ws[4], cm * v1.x); ws[5] = fmaf(am, ws[5], cm * v1.y);
      ws[6] = fmaf(am, ws[6], cm * v1.z); ws[7] = fmaf(am, ws[7], cm * v1.w);
    }
    __syncthreads();
  }
  // write att in [B,S,E] row-major: row = b*512 + s, col = h*64 + d
  const int b = bh >> 3, h = bh & 7;
  float* o = att + (((size_t)b * 512 + i0 + row_blk) * 512 + h * 64 + d0);
  float4 s0; s0.x = ws[0]; s0.y = ws[1]; s0.z = ws[2]; s0.w = ws[3];
  float4 s1; s1.x = ws[4]; s1.y = ws[5]; s1.z = ws[6]; s1.w = ws[7];
  *(float4*)&o[0] = s0;
  *(float4*)&o[4] = s1;
}

extern "C" void kernel_launch(void* const* d_in, const int* in_sizes, int n_in,
                              void* d_out, int out_size, void* d_ws, size_t ws_size,
                              hipStream_t stream) {
  const float* query = (const float*)d_in[0];
  const float* key_  = (const float*)d_in[1];
  const float* value = (const float*)d_in[2];
  const float* Wq = (const float*)d_in[3];
  const float* bq = (const float*)d_in[4];
  const float* Wk = (const float*)d_in[5];
  const float* bk = (const float*)d_in[6];
  const float* Wv = (const float*)d_in[7];
  const float* bv = (const float*)d_in[8];
  const float* Wo = (const float*)d_in[9];
  const float* bo = (const float*)d_in[10];
  float* ws = (float*)d_ws;
  const size_t M = 1u << 20;            // 1M floats
  float* Qb     = ws;                   // [32,512,64]
  float* Kb     = ws + 1 * M;
  float* Vb     = ws + 2 * M;
  float* qn     = ws + 3 * M;           // [32,512]
  float* kn     = qn + 16384;
  float* vn     = kn + 16384;
  float* rowsum = vn + 16384;           // [32,512]
  float* f3     = rowsum + 16384;       // [3,2048]
  float* fo     = f3 + 3 * 2048;        // [2048]
  float* rw     = ws + 4 * M;           // [32,512,512] unnormalized weights
  float* t3     = ws + 12 * M;          // 3x [2048,512]
  float* att    = ws + 15 * M;          // [2048,512] row-major [B,S,E]
  float* to_    = ws + 16 * M;          // [2048,512]

  hipMemsetAsync(rowsum, 0, 16384 * sizeof(float), stream);
  k_rownorm<<<dim3(2048, 3), 256, 0, stream>>>(query, key_, value, f3);
  k_gemm<<<dim3(32, 8, 3), 256, 0, stream>>>(query, key_, value, Wq, Wk, Wv, f3, t3);
  k_post<<<dim3(2048, 3), 256, 0, stream>>>(t3, bq, bk, bv, Qb, Kb, Vb, qn, kn, vn, 0);
  k_logits<<<dim3(8, 4, 32), 256, 0, stream>>>(Qb, Kb, qn, kn, rw, rowsum);
  k_scan<<<512, 256, 0, stream>>>(Vb, vn, rw, rowsum, att);
  k_rownorm<<<dim3(2048, 1), 256, 0, stream>>>(att, att, att, fo);
  k_gemm<<<dim3(32, 8, 1), 256, 0, stream>>>(att, att, att, Wo, Wo, Wo, fo, to_);
  k_post<<<dim3(2048, 1), 256, 0, stream>>>(to_, bo, bo, bo, (float*)d_out,
                                            nullptr, nullptr, nullptr, nullptr, nullptr, 1);
}

// Round 6
// 277.513 us; speedup vs baseline: 1.3249x; 1.1672x over previous
//
#include <hip/hip_runtime.h>
#include <math.h>

#define EPS  1e-5f
#define EPS2 1e-10f
#define MAXN (1.0f - EPS)

using short8  = __attribute__((ext_vector_type(8))) short;
using floatx4 = __attribute__((ext_vector_type(4))) float;

// DPP cross-lane: pure VALU, never touches the LDS pipe
template <int CTRL>
static __device__ __forceinline__ float qperm(float x) {
  return __int_as_float(__builtin_amdgcn_update_dpp(
      __float_as_int(x), __float_as_int(x), CTRL, 0xF, 0xF, false));
}
#define QP_XOR1    0xB1   // quad_perm [1,0,3,2]
#define QP_XOR2    0x4E   // quad_perm [2,3,0,1]
#define QP_HALFMIR 0x141  // row_half_mirror: lane -> lane^7 within 8

// RNE fp32 -> bf16 split helpers
static __device__ __forceinline__ short bf16_rne(float x) {
  unsigned u = __float_as_uint(x);
  unsigned r = u + 0x7FFFu + ((u >> 16) & 1u);
  return (short)(r >> 16);
}
static __device__ __forceinline__ float bf16_tof(short h) {
  return __uint_as_float(((unsigned)(unsigned short)h) << 16);
}

// ---------- block reduction helper (256 threads = 4 waves) ----------
static __device__ __forceinline__ float block_sum(float v, float* red4) {
#pragma unroll
  for (int m = 32; m; m >>= 1) v += __shfl_xor(v, m, 64);
  if ((threadIdx.x & 63) == 0) red4[threadIdx.x >> 6] = v;
  __syncthreads();
  v = red4[0] + red4[1] + red4[2] + red4[3];
  __syncthreads();
  return v;
}

// ---------- K1: row-norm -> logmap scale factor f ----------
__global__ __launch_bounds__(256) void k_rownorm(const float* __restrict__ s0,
                                                 const float* __restrict__ s1,
                                                 const float* __restrict__ s2,
                                                 float* __restrict__ f) {
  const int n = blockIdx.x, z = blockIdx.y, t = threadIdx.x;
  const float* src = (z == 0) ? s0 : ((z == 1) ? s1 : s2);
  const float2 xv = *(const float2*)&src[(size_t)n * 512 + 2 * t];
  __shared__ float red4[4];
  const float ss = block_sum(xv.x * xv.x + xv.y * xv.y, red4);
  if (t == 0) {
    const float r = sqrtf(fmaxf(ss, EPS2));
    float fv;
    if (r >= MAXN) {
      const float at = 0.5f * logf((r * (2.0f - EPS) + EPS) / (EPS * (1.0f + r)));
      fv = (1.0f + EPS) * at / r;
    } else {
      const float at = 0.5f * logf((1.0f + r) / (1.0f - r));
      fv = (1.0f + EPS) * at / r;
    }
    f[z * 2048 + n] = fv;
  }
}

// ---------- K2: C = f[row]*(A @ W^T) via 3-term bf16-split MFMA ----------
// a*b ~= hi_a*hi_b + hi_a*lo_b + lo_a*hi_b  (error ~2^-16 relative)
__global__ __launch_bounds__(256) void k_gemm_mfma(
    const float* __restrict__ A0, const float* __restrict__ A1, const float* __restrict__ A2,
    const float* __restrict__ W0, const float* __restrict__ W1, const float* __restrict__ W2,
    const float* __restrict__ fbase, float* __restrict__ Cbase) {
  const int z = blockIdx.z;
  const float* A = (z == 0) ? A0 : ((z == 1) ? A1 : A2);
  const float* W = (z == 0) ? W0 : ((z == 1) ? W1 : W2);
  float* C = Cbase + (size_t)z * (2048 * 512);
  __shared__ short Ahi[64][72], Alo[64][72], Whi[64][72], Wlo[64][72];
  const int t = threadIdx.x;
  const int n0 = blockIdx.x * 64;   // M offset (rows, 2048)
  const int m0 = blockIdx.y * 64;   // N offset (cols, 512)
  const int row = t >> 2, c0 = (t & 3) * 16;
  const int w = t >> 6, lane = t & 63;
  const int quad = lane >> 4, l16 = lane & 15;
  const int mw = (w & 1) * 32, nw = (w >> 1) * 32;
  floatx4 acc[2][2];
#pragma unroll
  for (int i = 0; i < 2; ++i)
#pragma unroll
    for (int j = 0; j < 2; ++j) acc[i][j] = (floatx4){0.f, 0.f, 0.f, 0.f};

  for (int k0 = 0; k0 < 512; k0 += 64) {
    float4 av[4], wv[4];
#pragma unroll
    for (int i = 0; i < 4; ++i) {
      av[i] = *(const float4*)&A[(size_t)(n0 + row) * 512 + k0 + c0 + 4 * i];
      wv[i] = *(const float4*)&W[(size_t)(m0 + row) * 512 + k0 + c0 + 4 * i];
    }
    __syncthreads();
#pragma unroll
    for (int i = 0; i < 4; ++i) {
      const float a4[4] = {av[i].x, av[i].y, av[i].z, av[i].w};
      const float w4[4] = {wv[i].x, wv[i].y, wv[i].z, wv[i].w};
#pragma unroll
      for (int e = 0; e < 4; ++e) {
        const short ah = bf16_rne(a4[e]);
        const short wh = bf16_rne(w4[e]);
        Ahi[row][c0 + 4 * i + e] = ah;
        Alo[row][c0 + 4 * i + e] = bf16_rne(a4[e] - bf16_tof(ah));
        Whi[row][c0 + 4 * i + e] = wh;
        Wlo[row][c0 + 4 * i + e] = bf16_rne(w4[e] - bf16_tof(wh));
      }
    }
    __syncthreads();
#pragma unroll
    for (int kk = 0; kk < 64; kk += 32) {
      short8 ah[2], al[2], bh[2], bl[2];
#pragma unroll
      for (int i = 0; i < 2; ++i) {
        ah[i] = *(const short8*)&Ahi[mw + i * 16 + l16][kk + quad * 8];
        al[i] = *(const short8*)&Alo[mw + i * 16 + l16][kk + quad * 8];
        bh[i] = *(const short8*)&Whi[nw + i * 16 + l16][kk + quad * 8];
        bl[i] = *(const short8*)&Wlo[nw + i * 16 + l16][kk + quad * 8];
      }
#pragma unroll
      for (int i = 0; i < 2; ++i)
#pragma unroll
        for (int j = 0; j < 2; ++j) {
          acc[i][j] = __builtin_amdgcn_mfma_f32_16x16x32_bf16(ah[i], bh[j], acc[i][j], 0, 0, 0);
          acc[i][j] = __builtin_amdgcn_mfma_f32_16x16x32_bf16(ah[i], bl[j], acc[i][j], 0, 0, 0);
          acc[i][j] = __builtin_amdgcn_mfma_f32_16x16x32_bf16(al[i], bh[j], acc[i][j], 0, 0, 0);
        }
    }
  }
#pragma unroll
  for (int i = 0; i < 2; ++i) {
    const int grow_base = n0 + mw + i * 16 + quad * 4;
#pragma unroll
    for (int r = 0; r < 4; ++r) {
      const float fv = fbase[z * 2048 + grow_base + r];
#pragma unroll
      for (int j = 0; j < 2; ++j)
        C[(size_t)(grow_base + r) * 512 + m0 + nw + j * 16 + l16] = fv * acc[i][j][r];
    }
  }
}

// ---------- K3: expmap0 + mobius-add bias; per-head project + norms ----------
__global__ __launch_bounds__(256) void k_post(const float* __restrict__ tin,
                                              const float* __restrict__ b0,
                                              const float* __restrict__ b1,
                                              const float* __restrict__ b2,
                                              float* __restrict__ o0, float* __restrict__ o1,
                                              float* __restrict__ o2,
                                              float* __restrict__ nrm0, float* __restrict__ nrm1,
                                              float* __restrict__ nrm2,
                                              float* __restrict__ rowsum_init, int final_mode) {
  const int nrow = blockIdx.x, z = blockIdx.y, t = threadIdx.x;
  const float* tv = tin + ((size_t)z * 2048 + nrow) * 512;
  const float* bias = (z == 0) ? b0 : ((z == 1) ? b1 : b2);
  const int e0 = 2 * t;
  const float2 tp = *(const float2*)&tv[e0];
  const float2 bp = *(const float2*)&bias[e0];
  float p_tt = tp.x * tp.x + tp.y * tp.y;
  float p_tb = tp.x * bp.x + tp.y * bp.y;
  float p_bb = bp.x * bp.x + bp.y * bp.y;
#pragma unroll
  for (int m = 32; m; m >>= 1) {
    p_tt += __shfl_xor(p_tt, m, 64);
    p_tb += __shfl_xor(p_tb, m, 64);
    p_bb += __shfl_xor(p_bb, m, 64);
  }
  __shared__ float red[4][3];
  const int lane = t & 63, w = t >> 6;
  if (lane == 0) { red[w][0] = p_tt; red[w][1] = p_tb; red[w][2] = p_bb; }
  __syncthreads();
  const float s_tt = red[0][0] + red[1][0] + red[2][0] + red[3][0];
  const float s_tb = red[0][1] + red[1][1] + red[2][1] + red[3][1];
  const float s_bb = red[0][2] + red[1][2] + red[2][2] + red[3][2];
  const float tn = sqrtf(fmaxf(s_tt, EPS2));
  const float th = tanhf(tn / (1.0f + EPS));
  const float g = th / tn;
  const float rnorm = th * (sqrtf(s_tt) / tn);
  const float sr = (rnorm >= MAXN) ? (MAXN / (rnorm + EPS)) : 1.0f;
  const float gr = g * sr;
  const float rn = (rnorm * sr) * (rnorm * sr);
  const float bnorm = sqrtf(fmaxf(s_bb, EPS2));
  const float sb = (bnorm >= MAXN) ? (MAXN / (bnorm + EPS)) : 1.0f;
  const float xy = gr * sb * s_tb;
  const float yn = (sb * sb) * s_bb;
  const float Af = 1.0f + 2.0f * xy + yn;
  const float Cf = 1.0f - rn;
  const float den = 1.0f + 2.0f * xy + rn * yn + EPS;
  const float id = 1.0f / den;
  const float on_raw = (Af * Af * rn + 2.0f * Af * Cf * xy + Cf * Cf * yn) * (id * id);
  const float no = sqrtf(fmaxf(on_raw, EPS2));
  const float so = (no >= MAXN) ? (MAXN / (no + EPS)) : 1.0f;
  const float ms = id * so;
  const float ca = gr * Af * ms;
  const float cb = sb * Cf * ms;
  const float v0 = ca * tp.x + cb * bp.x;
  const float v1 = ca * tp.y + cb * bp.y;
  if (final_mode) {
    float2 o; o.x = v0; o.y = v1;
    *(float2*)&o0[(size_t)nrow * 512 + e0] = o;
    return;
  }
  float hp = v0 * v0 + v1 * v1;
#pragma unroll
  for (int m = 16; m; m >>= 1) hp += __shfl_xor(hp, m, 64);
  const float hnr = sqrtf(fmaxf(hp, EPS2));
  float sh = 1.0f;
  if (z != 2) sh = (hnr >= MAXN) ? (MAXN / (hnr + EPS)) : 1.0f;
  float* outz = (z == 0) ? o0 : ((z == 1) ? o1 : o2);
  float* nz = (z == 0) ? nrm0 : ((z == 1) ? nrm1 : nrm2);
  const int b = nrow >> 9, s = nrow & 511, h = e0 >> 6, d = e0 & 63;
  float2 o; o.x = v0 * sh; o.y = v1 * sh;
  *(float2*)&outz[(((size_t)(b * 8 + h) * 512 + s) * 64 + d)] = o;
  if ((t & 31) == 0) nz[(size_t)(b * 8 + h) * 512 + s] = hp * sh * sh;
  // fold rowsum zero-init here (runs before k_logits on the stream)
  if (z == 0 && t < 8) rowsum_init[((size_t)(nrow >> 9) * 8 + t) * 512 + (nrow & 511)] = 0.0f;
}

// ---------- K4: r = exp(-dist) EXACTLY = 1/(z+sqrt(z^2-1)); row-sums via atomics ----------
__global__ __launch_bounds__(256) void k_logits(const float* __restrict__ Q,
                                                const float* __restrict__ K,
                                                const float* __restrict__ qn,
                                                const float* __restrict__ kn,
                                                float* __restrict__ attn,
                                                float* __restrict__ rowsum) {
  const int bh = blockIdx.z;
  const int i0 = blockIdx.x * 64;
  const int j0 = blockIdx.y * 128;
  const float* Qb = Q + (size_t)bh * 512 * 64;
  const float* Kb = K + (size_t)bh * 512 * 64;
  __shared__ __align__(16) float q_lds[64][68];
  __shared__ __align__(16) float k_lds[128][68];
  const int t = threadIdx.x;
  const int tx = t & 15, ty = t >> 4;
  const int tx4 = tx * 4;
#pragma unroll
  for (int it = 0; it < 4; ++it) {
    const int row = it * 16 + ty;
    *(float4*)&q_lds[row][tx4] = *(const float4*)&Qb[(size_t)(i0 + row) * 64 + tx4];
  }
#pragma unroll
  for (int it = 0; it < 8; ++it) {
    const int row = it * 16 + ty;
    *(float4*)&k_lds[row][tx4] = *(const float4*)&Kb[(size_t)(j0 + row) * 64 + tx4];
  }
  __syncthreads();
  float acc[4][8] = {};
#pragma unroll
  for (int d = 0; d < 64; d += 4) {
    float4 qv[4], kv[8];
#pragma unroll
    for (int i = 0; i < 4; ++i) qv[i] = *(const float4*)&q_lds[ty * 4 + i][d];
#pragma unroll
    for (int j = 0; j < 8; ++j) kv[j] = *(const float4*)&k_lds[tx + 16 * j][d];
#pragma unroll
    for (int i = 0; i < 4; ++i)
#pragma unroll
      for (int j = 0; j < 8; ++j) {
        acc[i][j] = fmaf(qv[i].x, kv[j].x, acc[i][j]);
        acc[i][j] = fmaf(qv[i].y, kv[j].y, acc[i][j]);
        acc[i][j] = fmaf(qv[i].z, kv[j].z, acc[i][j]);
        acc[i][j] = fmaf(qv[i].w, kv[j].w, acc[i][j]);
      }
  }
  float qni[4], knj[8];
#pragma unroll
  for (int i = 0; i < 4; ++i) qni[i] = qn[(size_t)bh * 512 + i0 + ty * 4 + i];
#pragma unroll
  for (int j = 0; j < 8; ++j) knj[j] = kn[(size_t)bh * 512 + j0 + tx + 16 * j];
  float rs_[4] = {};
#pragma unroll
  for (int i = 0; i < 4; ++i)
#pragma unroll
    for (int j = 0; j < 8; ++j) {
      const float num = fmaxf(qni[i] + knj[j] - 2.0f * acc[i][j], 0.0f);
      const float den = fmaxf((1.0f - qni[i]) * (1.0f - knj[j]), EPS);
      const float wv = 2.0f * num / den + EPS;
      const float s_ = 1.0f + wv + sqrtf(wv * (wv + 2.0f));
      const float r = __builtin_amdgcn_rcpf(s_);
      rs_[i] += r;
      attn[((size_t)bh * 512 + i0 + ty * 4 + i) * 512 + j0 + tx + 16 * j] = r;
    }
#pragma unroll
  for (int i = 0; i < 4; ++i) {
    float v = rs_[i];
    v += __shfl_xor(v, 1, 64); v += __shfl_xor(v, 2, 64);
    v += __shfl_xor(v, 4, 64); v += __shfl_xor(v, 8, 64);
    if (tx == 0) atomicAdd(&rowsum[(size_t)bh * 512 + i0 + ty * 4 + i], v);
  }
}

// ---------- K6 v6: mobius scan, 8 lanes/row, FULL inner unroll ----------
// Full unroll makes all LDS offsets compile-time immediates (ds_read offset:N),
// removing per-step address VALU + loop overhead.
__global__ __launch_bounds__(256) void k_scan(const float* __restrict__ V,
                                              const float* __restrict__ vn,
                                              const float* __restrict__ rw,
                                              const float* __restrict__ rowsum,
                                              float* __restrict__ att) {
  __shared__ __align__(16) float v_lds[64 * 64];
  __shared__ __align__(16) float swyn_lds[64 * 66];
  const int blk = blockIdx.x;
  const int bh = blk >> 4;
  const int i0 = (blk & 15) * 32;
  const int t = threadIdx.x;
  const int lane = t & 63, w = t >> 6;
  const int row_blk = w * 8 + (lane >> 3);
  const int sub = lane & 7;
  const int d0 = sub * 8;
  const float* Vb = V + (size_t)bh * 512 * 64;
  const float* vnb = vn + (size_t)bh * 512;
  const float* arow = rw + ((size_t)bh * 512 + i0 + row_blk) * 512;
  const float inv_s = __builtin_amdgcn_rcpf(rowsum[(size_t)bh * 512 + i0 + row_blk]);

  float ws[8];
#pragma unroll
  for (int k = 0; k < 8; ++k) ws[k] = 0.0f;
  float xn = 0.0f;

  for (int jc = 0; jc < 512; jc += 64) {
#pragma unroll
    for (int it = 0; it < 4; ++it) {
      const int idx4 = it * 256 + t;
      *(float4*)&v_lds[idx4 * 4] = *(const float4*)&Vb[(size_t)jc * 64 + idx4 * 4];
    }
    const float4 a0 = *(const float4*)&arow[jc + sub * 8];
    const float4 a1 = *(const float4*)&arow[jc + sub * 8 + 4];
    const float4 n0 = *(const float4*)&vnb[jc + sub * 8];
    const float4 n1 = *(const float4*)&vnb[jc + sub * 8 + 4];
    const float wq[8] = {a0.x, a0.y, a0.z, a0.w, a1.x, a1.y, a1.z, a1.w};
    const float nq[8] = {n0.x, n0.y, n0.z, n0.w, n1.x, n1.y, n1.z, n1.w};
#pragma unroll
    for (int e = 0; e < 8; ++e) {
      const float wgt = wq[e] * inv_s;
      float2 p; p.x = wgt; p.y = (wgt * wgt) * nq[e];
      *(float2*)&swyn_lds[(sub * 8 + e) * 66 + row_blk * 2] = p;
    }
    __syncthreads();

#pragma unroll
    for (int j = 0; j < 64; ++j) {
      const float2 sy2 = *(const float2*)&swyn_lds[j * 66 + row_blk * 2];
      const float4 v0 = *(const float4*)&v_lds[j * 64 + d0];
      const float4 v1 = *(const float4*)&v_lds[j * 64 + d0 + 4];
      float da = ws[0] * v0.x;
      da = fmaf(ws[1], v0.y, da); da = fmaf(ws[2], v0.z, da); da = fmaf(ws[3], v0.w, da);
      float db = ws[4] * v1.x;
      db = fmaf(ws[5], v1.y, db); db = fmaf(ws[6], v1.z, db); db = fmaf(ws[7], v1.w, db);
      float d = da + db;
      d += qperm<QP_XOR1>(d);
      d += qperm<QP_XOR2>(d);
      d += qperm<QP_HALFMIR>(d);         // dot(ws, v_j) across the 8-lane row
      const float sw = sy2.x, yn = sy2.y;
      const float ynp1 = 1.0f + yn;
      const float xy = sw * d;
      const float Cf = 1.0f - xn;
      const float den = fmaf(2.0f, xy, fmaf(xn, yn, 1.0f + EPS));
      const float Af = fmaf(2.0f, xy, ynp1);
      const float id = __builtin_amdgcn_rcpf(den);
      const float A2 = Af * Af, CC = Cf * Cf, AC = Af * Cf;
      const float txy = xy + xy;
      const float onn = fmaf(A2, xn, fmaf(CC, yn, txy * AC));
      const float id2 = id * id;
      xn = onn * id2;                    // ||out||^2; in-ball by gyro-triangle bound
      const float am = Af * id;
      const float cm = (Cf * sw) * id;
      ws[0] = fmaf(am, ws[0], cm * v0.x); ws[1] = fmaf(am, ws[1], cm * v0.y);
      ws[2] = fmaf(am, ws[2], cm * v0.z); ws[3] = fmaf(am, ws[3], cm * v0.w);
      ws[4] = fmaf(am, ws[4], cm * v1.x); ws[5] = fmaf(am, ws[5], cm * v1.y);
      ws[6] = fmaf(am, ws[6], cm * v1.z); ws[7] = fmaf(am, ws[7], cm * v1.w);
    }
    __syncthreads();
  }
  // write att in [B,S,E] row-major: row = b*512 + s, col = h*64 + d
  const int b = bh >> 3, h = bh & 7;
  float* o = att + (((size_t)b * 512 + i0 + row_blk) * 512 + h * 64 + d0);
  float4 s0; s0.x = ws[0]; s0.y = ws[1]; s0.z = ws[2]; s0.w = ws[3];
  float4 s1; s1.x = ws[4]; s1.y = ws[5]; s1.z = ws[6]; s1.w = ws[7];
  *(float4*)&o[0] = s0;
  *(float4*)&o[4] = s1;
}

extern "C" void kernel_launch(void* const* d_in, const int* in_sizes, int n_in,
                              void* d_out, int out_size, void* d_ws, size_t ws_size,
                              hipStream_t stream) {
  const float* query = (const float*)d_in[0];
  const float* key_  = (const float*)d_in[1];
  const float* value = (const float*)d_in[2];
  const float* Wq = (const float*)d_in[3];
  const float* bq = (const float*)d_in[4];
  const float* Wk = (const float*)d_in[5];
  const float* bk = (const float*)d_in[6];
  const float* Wv = (const float*)d_in[7];
  const float* bv = (const float*)d_in[8];
  const float* Wo = (const float*)d_in[9];
  const float* bo = (const float*)d_in[10];
  float* ws = (float*)d_ws;
  const size_t M = 1u << 20;            // 1M floats
  float* Qb     = ws;                   // [32,512,64]
  float* Kb     = ws + 1 * M;
  float* Vb     = ws + 2 * M;
  float* qn     = ws + 3 * M;           // [32,512]
  float* kn     = qn + 16384;
  float* vn     = kn + 16384;
  float* rowsum = vn + 16384;           // [32,512]
  float* f3     = rowsum + 16384;       // [3,2048]
  float* fo     = f3 + 3 * 2048;        // [2048]
  float* rw     = ws + 4 * M;           // [32,512,512] unnormalized weights
  float* t3     = ws + 12 * M;          // 3x [2048,512]
  float* att    = ws + 15 * M;          // [2048,512] row-major [B,S,E]
  float* to_    = ws + 16 * M;          // [2048,512]

  k_rownorm<<<dim3(2048, 3), 256, 0, stream>>>(query, key_, value, f3);
  k_gemm_mfma<<<dim3(32, 8, 3), 256, 0, stream>>>(query, key_, value, Wq, Wk, Wv, f3, t3);
  k_post<<<dim3(2048, 3), 256, 0, stream>>>(t3, bq, bk, bv, Qb, Kb, Vb, qn, kn, vn,
                                            rowsum, 0);
  k_logits<<<dim3(8, 4, 32), 256, 0, stream>>>(Qb, Kb, qn, kn, rw, rowsum);
  k_scan<<<512, 256, 0, stream>>>(Vb, vn, rw, rowsum, att);
  k_rownorm<<<dim3(2048, 1), 256, 0, stream>>>(att, att, att, fo);
  k_gemm_mfma<<<dim3(32, 8, 1), 256, 0, stream>>>(att, att, att, Wo, Wo, Wo, fo, to_);
  k_post<<<dim3(2048, 1), 256, 0, stream>>>(to_, bo, bo, bo, (float*)d_out,
                                            nullptr, nullptr, nullptr, nullptr, nullptr,
                                            nullptr, 1);
}